// Round 3
// baseline (1000.417 us; speedup 1.0000x reference)
//
#include <hip/hip_runtime.h>

#define NN 50000
#define NE 800000
#define NGR 256

// ---------------- CSR build ----------------
__global__ void k_deg(const int* __restrict__ dst, int* __restrict__ deg, int E) {
    int i = blockIdx.x * 256 + threadIdx.x;
    if (i < E) atomicAdd(&deg[dst[i]], 1);
}

__global__ void k_scan1(const int* __restrict__ deg, int* __restrict__ rowp,
                        int* __restrict__ bsum, int M) {
    __shared__ int sm[256];
    int t = threadIdx.x, i = blockIdx.x * 256 + t;
    int v = (i < M) ? deg[i] + 1 : 0;   // +1 self loop
    sm[t] = v; __syncthreads();
    for (int off = 1; off < 256; off <<= 1) {
        int x = (t >= off) ? sm[t - off] : 0;
        __syncthreads();
        sm[t] += x;
        __syncthreads();
    }
    if (i < M) rowp[i] = sm[t] - v;     // exclusive
    if (t == 255) bsum[blockIdx.x] = sm[255];
}

__global__ void k_scan2(int* bsum, int NB) {
    __shared__ int sm[256];
    int t = threadIdx.x;
    int v = (t < NB) ? bsum[t] : 0;
    sm[t] = v; __syncthreads();
    for (int off = 1; off < 256; off <<= 1) {
        int x = (t >= off) ? sm[t - off] : 0;
        __syncthreads();
        sm[t] += x;
        __syncthreads();
    }
    if (t < NB) bsum[t] = sm[t] - v;    // exclusive block offsets
}

__global__ void k_scan3(int* rowp, const int* __restrict__ bsum, int M, int total) {
    int i = blockIdx.x * 256 + threadIdx.x;
    if (i < M) rowp[i] += bsum[blockIdx.x];
    if (i == 0) rowp[M] = total;
}

__global__ void k_fill(const int* __restrict__ src, const int* __restrict__ dst,
                       const int* __restrict__ rowp, int* __restrict__ cur,
                       int* __restrict__ colv, int E, int M) {
    int i = blockIdx.x * 256 + threadIdx.x;
    if (i < E) {
        int d = dst[i];
        int pos = rowp[d] + atomicAdd(&cur[d], 1);
        colv[pos] = src[i];
    } else if (i < E + M) {
        int nn = i - E;
        int pos = rowp[nn] + atomicAdd(&cur[nn], 1);
        colv[pos] = nn;
    }
}

// ---------------- simple tiled GEMM: H = A @ W (all fp32) ----------------
template<int KD>
__global__ __launch_bounds__(256)
void k_sgemm(const float* __restrict__ A, const float* __restrict__ Wp,
             float* __restrict__ Hout, int M, int NC) {
    __shared__ float As[64][17];
    __shared__ float Ws[16][65];
    const int tid = threadIdx.x;
    const int tx = tid & 15, ty = tid >> 4;
    const int m0 = blockIdx.x * 64, n0 = blockIdx.y * 64;
    float acc[4][4] = {};
    for (int k0 = 0; k0 < KD; k0 += 16) {
        #pragma unroll
        for (int l = 0; l < 4; ++l) {          // A tile: 64 x 16
            int idx = l * 256 + tid;
            int r = idx >> 4, c = idx & 15;
            int gm = m0 + r;
            As[r][c] = (gm < M) ? A[(size_t)gm * KD + k0 + c] : 0.f;
        }
        #pragma unroll
        for (int l = 0; l < 4; ++l) {          // W tile: 16 x 64
            int idx = l * 256 + tid;
            int r = idx >> 6, c = idx & 63;
            Ws[r][c] = Wp[(size_t)(k0 + r) * NC + n0 + c];
        }
        __syncthreads();
        #pragma unroll
        for (int kk = 0; kk < 16; ++kk) {
            float a[4], w[4];
            #pragma unroll
            for (int i = 0; i < 4; ++i) a[i] = As[ty * 4 + i][kk];
            #pragma unroll
            for (int j = 0; j < 4; ++j) w[j] = Ws[kk][tx * 4 + j];
            #pragma unroll
            for (int i = 0; i < 4; ++i)
                #pragma unroll
                for (int j = 0; j < 4; ++j)
                    acc[i][j] += a[i] * w[j];
        }
        __syncthreads();
    }
    #pragma unroll
    for (int i = 0; i < 4; ++i) {
        int gm = m0 + ty * 4 + i;
        if (gm < M) {
            #pragma unroll
            for (int j = 0; j < 4; ++j)
                Hout[(size_t)gm * NC + n0 + tx * 4 + j] = acc[i][j];
        }
    }
}

// ---------------- attention logits: al_s/al_d [N][H] ----------------
template<int H>
__global__ __launch_bounds__(256)
void k_al(const float* __restrict__ h, const float* __restrict__ a_s,
          const float* __restrict__ a_d, float* __restrict__ als,
          float* __restrict__ ald, int M) {
    int node = blockIdx.x * 4 + (threadIdx.x >> 6);
    if (node >= M) return;
    int lane = threadIdx.x & 63;
    constexpr int HC = H * 64;
    float ss[H], dd[H];
    #pragma unroll
    for (int j = 0; j < H; ++j) {
        float hv = h[(size_t)node * HC + j * 64 + lane];
        float ps = hv * a_s[j * 64 + lane];
        float pd = hv * a_d[j * 64 + lane];
        #pragma unroll
        for (int off = 32; off; off >>= 1) {
            ps += __shfl_xor(ps, off);
            pd += __shfl_xor(pd, off);
        }
        ss[j] = ps; dd[j] = pd;
    }
    if (lane == 0) {
        #pragma unroll
        for (int j = 0; j < H; ++j) {
            als[node * H + j] = ss[j];
            ald[node * H + j] = dd[j];
        }
    }
}

// ---------------- aggregation + bias + BN + ELU (wave per dst node) ----------------
template<int H>
__global__ __launch_bounds__(256)
void k_agg(const float* __restrict__ h, const float* __restrict__ als,
           const float* __restrict__ ald, const int* __restrict__ rowp,
           const int* __restrict__ colv,
           const float* __restrict__ bias, const float* __restrict__ gam,
           const float* __restrict__ bet, const float* __restrict__ mu,
           const float* __restrict__ var, float* __restrict__ xout, int M) {
    constexpr int HC = H * 64;
    constexpr int LPH = 64 / H;     // lanes per head group (pass A parallelism)
    constexpr int D = HC / 64;      // dims per lane in pass B
    int node = blockIdx.x * 4 + (threadIdx.x >> 6);
    if (node >= M) return;
    int lane = threadIdx.x & 63;
    int rs = rowp[node], re = rowp[node + 1];
    int hh = lane / LPH;
    float ad = ald[node * H + hh];
    // pass A: per-head max of leaky_relu(al_s[src]+al_d[dst])
    float mx = -3.0e38f;
    for (int i = rs + (lane % LPH); i < re; i += LPH) {
        int s = colv[i];
        float e = als[s * H + hh] + ad;
        e = e > 0.f ? e : 0.2f * e;
        mx = fmaxf(mx, e);
    }
    #pragma unroll
    for (int off = LPH >> 1; off; off >>= 1) mx = fmaxf(mx, __shfl_xor(mx, off));
    // pass B: den = sum(ee), acc = sum(ee * h[src])
    float den = 0.f;
    float acc[D] = {0.f};
    for (int i = rs; i < re; ++i) {
        int s = colv[i];
        float e = als[s * H + hh] + ad;
        e = e > 0.f ? e : 0.2f * e;
        float ee = __expf(e - mx);
        den += ee;
        if constexpr (D == 4) {
            const float4 hv = *(const float4*)(h + (size_t)s * HC + lane * 4);
            acc[0] += ee * hv.x; acc[1] += ee * hv.y;
            acc[2] += ee * hv.z; acc[3] += ee * hv.w;
        } else {
            acc[0] += ee * h[(size_t)s * HC + lane];
        }
    }
    float inv = 1.f / (den + 1e-16f);
    #pragma unroll
    for (int j = 0; j < D; ++j) {
        int d = lane * D + j;
        float o = acc[j] * inv + bias[d];
        float bn = (o - mu[d]) * rsqrtf(var[d] + 1e-5f) * gam[d] + bet[d];
        float el = bn > 0.f ? bn : (__expf(bn) - 1.f);
        xout[(size_t)node * HC + d] = el;
    }
}

// ---------------- pooling (block per graph, batch sorted -> binary search) ----------------
__global__ void k_pool(const float* __restrict__ x, const int* __restrict__ batch,
                       float* __restrict__ pooled, int M) {
    int g = blockIdx.x, lane = threadIdx.x; // 64 threads
    int lo = 0, hi = M;
    while (lo < hi) { int mid = (lo + hi) >> 1; if (batch[mid] < g) lo = mid + 1; else hi = mid; }
    int s = lo;
    lo = 0; hi = M;
    while (lo < hi) { int mid = (lo + hi) >> 1; if (batch[mid] < g + 1) lo = mid + 1; else hi = mid; }
    int e = lo;
    float sum = 0.f, mx = -3.0e38f;
    for (int n = s; n < e; ++n) {
        float v = x[(size_t)n * 64 + lane];
        sum += v; mx = fmaxf(mx, v);
    }
    int cnt = e - s;
    float mean = sum / (float)(cnt > 1 ? cnt : 1);
    if (cnt == 0) mx = 0.f;
    pooled[g * 192 + lane] = mean;
    pooled[g * 192 + 64 + lane] = mx;
    pooled[g * 192 + 128 + lane] = sum;
}

// ---------------- final MLP ----------------
__global__ void k_fc(const float* __restrict__ pooled,
                     const float* __restrict__ fc1w, const float* __restrict__ fc1b,
                     const float* __restrict__ fc2w, const float* __restrict__ fc2b,
                     const float* __restrict__ fc3w, const float* __restrict__ fc3b,
                     float* __restrict__ out) {
    __shared__ float hb[192];
    __shared__ float h1[64];
    __shared__ float h2[32];
    int g = blockIdx.x, t = threadIdx.x; // 64 threads
    for (int j = t; j < 192; j += 64) hb[j] = pooled[g * 192 + j];
    __syncthreads();
    float s = fc1b[t];
    for (int k = 0; k < 192; ++k) s += hb[k] * fc1w[k * 64 + t];
    h1[t] = fmaxf(s, 0.f);
    __syncthreads();
    if (t < 32) {
        float s2 = fc2b[t];
        for (int k = 0; k < 64; ++k) s2 += h1[k] * fc2w[k * 32 + t];
        h2[t] = fmaxf(s2, 0.f);
    }
    __syncthreads();
    if (t == 0) {
        float s3 = fc3b[0];
        for (int k = 0; k < 32; ++k) s3 += h2[k] * fc3w[k];
        out[g] = s3;
    }
}

extern "C" void kernel_launch(void* const* d_in, const int* in_sizes, int n_in,
                              void* d_out, int out_size, void* d_ws, size_t ws_size,
                              hipStream_t stream) {
    const float* x0     = (const float*)d_in[0];
    const int* ei       = (const int*)d_in[1];
    const int* batch    = (const int*)d_in[2];
    const float* W[3]   = {(const float*)d_in[3],  (const float*)d_in[11], (const float*)d_in[19]};
    const float* AS[3]  = {(const float*)d_in[4],  (const float*)d_in[12], (const float*)d_in[20]};
    const float* AD[3]  = {(const float*)d_in[5],  (const float*)d_in[13], (const float*)d_in[21]};
    const float* BI[3]  = {(const float*)d_in[6],  (const float*)d_in[14], (const float*)d_in[22]};
    const float* GA[3]  = {(const float*)d_in[7],  (const float*)d_in[15], (const float*)d_in[23]};
    const float* BE[3]  = {(const float*)d_in[8],  (const float*)d_in[16], (const float*)d_in[24]};
    const float* MU[3]  = {(const float*)d_in[9],  (const float*)d_in[17], (const float*)d_in[25]};
    const float* VA[3]  = {(const float*)d_in[10], (const float*)d_in[18], (const float*)d_in[26]};
    const float* fc1w = (const float*)d_in[27];
    const float* fc1b = (const float*)d_in[28];
    const float* fc2w = (const float*)d_in[29];
    const float* fc2b = (const float*)d_in[30];
    const float* fc3w = (const float*)d_in[31];
    const float* fc3b = (const float*)d_in[32];

    // control arrays first (fail loudly, not silently, if ws is short)
    char* ws = (char*)d_ws;
    int*   rowp   = (int*)  (ws);                      // 200,004 B
    int*   cur    = (int*)  (ws + 262144);             // 200,000 B
    int*   colv   = (int*)  (ws + 524288);             // 3,400,000 B
    int*   bsum   = (int*)  (ws + 4194304);            // 1,024 B
    float* als    = (float*)(ws + 4198400);            // 800,000 B
    float* ald    = (float*)(ws + 4998400);            // 800,000 B
    float* pooled = (float*)(ws + 5798400);            // 196,608 B
    float* h_buf  = (float*)(ws + 6291456);            // 51,200,000 B
    float* x_buf  = (float*)(ws + 57491456);           // 51,200,000 B  (end ~108.7 MB)

    const int* esrc = ei;
    const int* edst = ei + NE;
    const int NB_SCAN = (NN + 255) / 256; // 196

    // CSR build
    hipMemsetAsync(cur, 0, NN * sizeof(int), stream);
    k_deg<<<(NE + 255) / 256, 256, 0, stream>>>(edst, cur, NE);
    k_scan1<<<NB_SCAN, 256, 0, stream>>>(cur, rowp, bsum, NN);
    k_scan2<<<1, 256, 0, stream>>>(bsum, NB_SCAN);
    k_scan3<<<NB_SCAN, 256, 0, stream>>>(rowp, bsum, NN, NE + NN);
    hipMemsetAsync(cur, 0, NN * sizeof(int), stream);
    k_fill<<<(NE + NN + 255) / 256, 256, 0, stream>>>(esrc, edst, rowp, cur, colv, NE, NN);

    const int GX = (NN + 63) / 64; // 782
    int nwb = (NN + 3) / 4;

    // ---- layer 0 (K=128, HC=256, H=4)
    k_sgemm<128><<<dim3(GX, 4), 256, 0, stream>>>(x0, W[0], h_buf, NN, 256);
    k_al<4><<<nwb, 256, 0, stream>>>(h_buf, AS[0], AD[0], als, ald, NN);
    k_agg<4><<<nwb, 256, 0, stream>>>(h_buf, als, ald, rowp, colv,
                                      BI[0], GA[0], BE[0], MU[0], VA[0], x_buf, NN);
    // ---- layer 1 (K=256, HC=256, H=4)
    k_sgemm<256><<<dim3(GX, 4), 256, 0, stream>>>(x_buf, W[1], h_buf, NN, 256);
    k_al<4><<<nwb, 256, 0, stream>>>(h_buf, AS[1], AD[1], als, ald, NN);
    k_agg<4><<<nwb, 256, 0, stream>>>(h_buf, als, ald, rowp, colv,
                                      BI[1], GA[1], BE[1], MU[1], VA[1], x_buf, NN);
    // ---- layer 2 (K=256, HC=64, H=1)
    k_sgemm<256><<<dim3(GX, 1), 256, 0, stream>>>(x_buf, W[2], h_buf, NN, 64);
    k_al<1><<<nwb, 256, 0, stream>>>(h_buf, AS[2], AD[2], als, ald, NN);
    k_agg<1><<<nwb, 256, 0, stream>>>(h_buf, als, ald, rowp, colv,
                                      BI[2], GA[2], BE[2], MU[2], VA[2], x_buf, NN);

    // readout + MLP
    k_pool<<<NGR, 64, 0, stream>>>(x_buf, batch, pooled, NN);
    k_fc<<<NGR, 64, 0, stream>>>(pooled, fc1w, fc1b, fc2w, fc2b, fc3w, fc3b,
                                 (float*)d_out);
    (void)in_sizes; (void)n_in; (void)out_size; (void)ws_size;
}

// Round 4
// 810.086 us; speedup vs baseline: 1.2350x; 1.2350x over previous
//
#include <hip/hip_runtime.h>

typedef unsigned short ushort_t;
typedef unsigned int uint_t;
typedef __attribute__((ext_vector_type(8))) short short8;
typedef __attribute__((ext_vector_type(4))) float f32x4;

#define NN 50000
#define NE 800000
#define NGR 256

__device__ __forceinline__ ushort_t f2b_rn(float f) {
    uint_t u = __float_as_uint(f);
    return (ushort_t)((u + 0x7fffu + ((u >> 16) & 1u)) >> 16);
}

// ---------------- CSR build ----------------
__global__ void k_deg(const int* __restrict__ dst, int* __restrict__ deg, int E) {
    int i = blockIdx.x * 256 + threadIdx.x;
    if (i < E) atomicAdd(&deg[dst[i]], 1);
}

__global__ void k_scan1(const int* __restrict__ deg, int* __restrict__ rowp,
                        int* __restrict__ bsum, int M) {
    __shared__ int sm[256];
    int t = threadIdx.x, i = blockIdx.x * 256 + t;
    int v = (i < M) ? deg[i] + 1 : 0;   // +1 self loop
    sm[t] = v; __syncthreads();
    for (int off = 1; off < 256; off <<= 1) {
        int x = (t >= off) ? sm[t - off] : 0;
        __syncthreads();
        sm[t] += x;
        __syncthreads();
    }
    if (i < M) rowp[i] = sm[t] - v;     // exclusive
    if (t == 255) bsum[blockIdx.x] = sm[255];
}

__global__ void k_scan2(int* bsum, int NB) {
    __shared__ int sm[256];
    int t = threadIdx.x;
    int v = (t < NB) ? bsum[t] : 0;
    sm[t] = v; __syncthreads();
    for (int off = 1; off < 256; off <<= 1) {
        int x = (t >= off) ? sm[t - off] : 0;
        __syncthreads();
        sm[t] += x;
        __syncthreads();
    }
    if (t < NB) bsum[t] = sm[t] - v;    // exclusive block offsets
}

__global__ void k_scan3(int* rowp, const int* __restrict__ bsum, int M, int total) {
    int i = blockIdx.x * 256 + threadIdx.x;
    if (i < M) rowp[i] += bsum[blockIdx.x];
    if (i == 0) rowp[M] = total;
}

__global__ void k_fill(const int* __restrict__ src, const int* __restrict__ dst,
                       const int* __restrict__ rowp, int* __restrict__ cur,
                       int* __restrict__ colv, int E, int M) {
    int i = blockIdx.x * 256 + threadIdx.x;
    if (i < E) {
        int d = dst[i];
        int pos = rowp[d] + atomicAdd(&cur[d], 1);
        colv[pos] = src[i];
    } else if (i < E + M) {
        int nn = i - E;
        int pos = rowp[nn] + atomicAdd(&cur[nn], 1);
        colv[pos] = nn;
    }
}

// -------- weight transpose + hi/lo bf16 split: W[K][NC] fp32 -> wT{h,l}[NC][K] --------
__global__ void k_wsplit(const float* __restrict__ W, ushort_t* __restrict__ th,
                         ushort_t* __restrict__ tl, int K, int NC) {
    int i = blockIdx.x * 256 + threadIdx.x;
    if (i < K * NC) {
        int k = i / NC, n = i % NC;
        float f = W[i];
        uint_t u = __float_as_uint(f);
        ushort_t hi = (ushort_t)(u >> 16);                       // truncate
        float rem = f - __uint_as_float(u & 0xffff0000u);
        th[n * K + k] = hi;
        tl[n * K + k] = f2b_rn(rem);
    }
}

// ---------------- MFMA GEMM: H = A @ W via split-bf16 ----------------
// A[M][KD] fp32 (split to hi/lo bf16 during staging); Bt{h,l} = wT [NC][KD] bf16.
// acc = Ah*Bh + Ah*Bl + Al*Bh  (lo*lo dropped, ~2^-16 rel)
template<int KD, int BN>
__global__ __launch_bounds__(256)
void k_mgemm(const float* __restrict__ A, const ushort_t* __restrict__ Bth,
             const ushort_t* __restrict__ Btl, float* __restrict__ Hout,
             int M, int NC) {
    constexpr int BM = 128, BK = 32, P = 40;
    __shared__ ushort_t Ah[BM * P];
    __shared__ ushort_t Al[BM * P];
    __shared__ ushort_t Bh[BN * P];
    __shared__ ushort_t Bl[BN * P];
    const int tid = threadIdx.x;
    const int m0 = blockIdx.x * BM;
    const int n0 = blockIdx.y * BN;
    const int wave = tid >> 6, lane = tid & 63;
    const int lrow = lane & 15, lq = lane >> 4;
    constexpr int RT = (BN == 128) ? 4 : 2;
    int wm, wn;
    if constexpr (BN == 128) { wm = (wave >> 1) * 64; wn = (wave & 1) * 64; }
    else                     { wm = wave * 32;        wn = 0; }

    f32x4 acc[RT][4] = {};

    for (int k0 = 0; k0 < KD; k0 += BK) {
        // ---- stage A tile (fp32 -> hi/lo bf16)
        #pragma unroll
        for (int it = 0; it < 4; ++it) {
            int idx = (it * 256 + tid) * 4;
            int r = idx >> 5, kk = idx & 31;
            int gm = m0 + r;
            float4 v = make_float4(0.f, 0.f, 0.f, 0.f);
            if (gm < M) v = *(const float4*)(A + (size_t)gm * KD + (k0 + kk));
            float vv[4] = {v.x, v.y, v.z, v.w};
            ushort_t hs[4], ls[4];
            #pragma unroll
            for (int j = 0; j < 4; ++j) {
                uint_t u = __float_as_uint(vv[j]);
                hs[j] = (ushort_t)(u >> 16);
                float rem = vv[j] - __uint_as_float(u & 0xffff0000u);
                ls[j] = f2b_rn(rem);
            }
            uint2 ph, pl;
            ph.x = (uint_t)hs[0] | ((uint_t)hs[1] << 16);
            ph.y = (uint_t)hs[2] | ((uint_t)hs[3] << 16);
            pl.x = (uint_t)ls[0] | ((uint_t)ls[1] << 16);
            pl.y = (uint_t)ls[2] | ((uint_t)ls[3] << 16);
            *(uint2*)&Ah[r * P + kk] = ph;
            *(uint2*)&Al[r * P + kk] = pl;
        }
        // ---- stage B tiles (bf16, rows of wT = output cols; always in-bounds)
        {
            constexpr int BITERS = BN / 64;
            #pragma unroll
            for (int it = 0; it < BITERS; ++it) {
                int idx = (it * 256 + tid) * 8;
                int r = idx >> 5, kk = idx & 31;
                uint4 vh = *(const uint4*)(Bth + (size_t)(n0 + r) * KD + (k0 + kk));
                uint4 vl = *(const uint4*)(Btl + (size_t)(n0 + r) * KD + (k0 + kk));
                *(uint4*)&Bh[r * P + kk] = vh;
                *(uint4*)&Bl[r * P + kk] = vl;
            }
        }
        __syncthreads();
        short8 afh[RT], afl[RT], bfh[4], bfl[4];
        #pragma unroll
        for (int r = 0; r < RT; ++r) {
            afh[r] = *(const short8*)&Ah[(wm + r * 16 + lrow) * P + lq * 8];
            afl[r] = *(const short8*)&Al[(wm + r * 16 + lrow) * P + lq * 8];
        }
        #pragma unroll
        for (int c = 0; c < 4; ++c) {
            bfh[c] = *(const short8*)&Bh[(wn + c * 16 + lrow) * P + lq * 8];
            bfl[c] = *(const short8*)&Bl[(wn + c * 16 + lrow) * P + lq * 8];
        }
        #pragma unroll
        for (int r = 0; r < RT; ++r)
            #pragma unroll
            for (int c = 0; c < 4; ++c) {
                acc[r][c] = __builtin_amdgcn_mfma_f32_16x16x32_bf16(afh[r], bfh[c], acc[r][c], 0, 0, 0);
                acc[r][c] = __builtin_amdgcn_mfma_f32_16x16x32_bf16(afh[r], bfl[c], acc[r][c], 0, 0, 0);
                acc[r][c] = __builtin_amdgcn_mfma_f32_16x16x32_bf16(afl[r], bfh[c], acc[r][c], 0, 0, 0);
            }
        __syncthreads();
    }
    // ---- epilogue: C/D layout col=lane&15, row=(lane>>4)*4+reg
    #pragma unroll
    for (int r = 0; r < RT; ++r) {
        #pragma unroll
        for (int c = 0; c < 4; ++c) {
            int colg = n0 + wn + c * 16 + lrow;
            #pragma unroll
            for (int j = 0; j < 4; ++j) {
                int row = m0 + wm + r * 16 + lq * 4 + j;
                if (row < M) Hout[(size_t)row * NC + colg] = acc[r][c][j];
            }
        }
    }
}

// ---------------- attention logits: al_s/al_d [N][H] ----------------
template<int H>
__global__ __launch_bounds__(256)
void k_al(const float* __restrict__ h, const float* __restrict__ a_s,
          const float* __restrict__ a_d, float* __restrict__ als,
          float* __restrict__ ald, int M) {
    int node = blockIdx.x * 4 + (threadIdx.x >> 6);
    if (node >= M) return;
    int lane = threadIdx.x & 63;
    constexpr int HC = H * 64;
    float ss[H], dd[H];
    #pragma unroll
    for (int j = 0; j < H; ++j) {
        float hv = h[(size_t)node * HC + j * 64 + lane];
        float ps = hv * a_s[j * 64 + lane];
        float pd = hv * a_d[j * 64 + lane];
        #pragma unroll
        for (int off = 32; off; off >>= 1) {
            ps += __shfl_xor(ps, off);
            pd += __shfl_xor(pd, off);
        }
        ss[j] = ps; dd[j] = pd;
    }
    if (lane == 0) {
        #pragma unroll
        for (int j = 0; j < H; ++j) {
            als[node * H + j] = ss[j];
            ald[node * H + j] = dd[j];
        }
    }
}

// ---------------- aggregation + bias + BN + ELU (wave per dst node) ----------------
template<int H>
__global__ __launch_bounds__(256)
void k_agg(const float* __restrict__ h, const float* __restrict__ als,
           const float* __restrict__ ald, const int* __restrict__ rowp,
           const int* __restrict__ colv,
           const float* __restrict__ bias, const float* __restrict__ gam,
           const float* __restrict__ bet, const float* __restrict__ mu,
           const float* __restrict__ var, float* __restrict__ xout, int M) {
    constexpr int HC = H * 64;
    constexpr int LPH = 64 / H;     // lanes per head group (pass A parallelism)
    constexpr int D = HC / 64;      // dims per lane in pass B
    int node = blockIdx.x * 4 + (threadIdx.x >> 6);
    if (node >= M) return;
    int lane = threadIdx.x & 63;
    int rs = rowp[node], re = rowp[node + 1];
    int hh = lane / LPH;
    float ad = ald[node * H + hh];
    // pass A: per-head max of leaky_relu(al_s[src]+al_d[dst])
    float mx = -3.0e38f;
    for (int i = rs + (lane % LPH); i < re; i += LPH) {
        int s = colv[i];
        float e = als[s * H + hh] + ad;
        e = e > 0.f ? e : 0.2f * e;
        mx = fmaxf(mx, e);
    }
    #pragma unroll
    for (int off = LPH >> 1; off; off >>= 1) mx = fmaxf(mx, __shfl_xor(mx, off));
    // pass B: den = sum(ee), acc = sum(ee * h[src])
    float den = 0.f;
    float acc[D] = {0.f};
    for (int i = rs; i < re; ++i) {
        int s = colv[i];
        float e = als[s * H + hh] + ad;
        e = e > 0.f ? e : 0.2f * e;
        float ee = __expf(e - mx);
        den += ee;
        if constexpr (D == 4) {
            const float4 hv = *(const float4*)(h + (size_t)s * HC + lane * 4);
            acc[0] += ee * hv.x; acc[1] += ee * hv.y;
            acc[2] += ee * hv.z; acc[3] += ee * hv.w;
        } else {
            acc[0] += ee * h[(size_t)s * HC + lane];
        }
    }
    float inv = 1.f / (den + 1e-16f);
    #pragma unroll
    for (int j = 0; j < D; ++j) {
        int d = lane * D + j;
        float o = acc[j] * inv + bias[d];
        float bn = (o - mu[d]) * rsqrtf(var[d] + 1e-5f) * gam[d] + bet[d];
        float el = bn > 0.f ? bn : (__expf(bn) - 1.f);
        xout[(size_t)node * HC + d] = el;
    }
}

// ---------------- pooling (block per graph, batch sorted -> binary search) ----------------
__global__ void k_pool(const float* __restrict__ x, const int* __restrict__ batch,
                       float* __restrict__ pooled, int M) {
    int g = blockIdx.x, lane = threadIdx.x; // 64 threads
    int lo = 0, hi = M;
    while (lo < hi) { int mid = (lo + hi) >> 1; if (batch[mid] < g) lo = mid + 1; else hi = mid; }
    int s = lo;
    lo = 0; hi = M;
    while (lo < hi) { int mid = (lo + hi) >> 1; if (batch[mid] < g + 1) lo = mid + 1; else hi = mid; }
    int e = lo;
    float sum = 0.f, mx = -3.0e38f;
    for (int n = s; n < e; ++n) {
        float v = x[(size_t)n * 64 + lane];
        sum += v; mx = fmaxf(mx, v);
    }
    int cnt = e - s;
    float mean = sum / (float)(cnt > 1 ? cnt : 1);
    if (cnt == 0) mx = 0.f;
    pooled[g * 192 + lane] = mean;
    pooled[g * 192 + 64 + lane] = mx;
    pooled[g * 192 + 128 + lane] = sum;
}

// ---------------- final MLP ----------------
__global__ void k_fc(const float* __restrict__ pooled,
                     const float* __restrict__ fc1w, const float* __restrict__ fc1b,
                     const float* __restrict__ fc2w, const float* __restrict__ fc2b,
                     const float* __restrict__ fc3w, const float* __restrict__ fc3b,
                     float* __restrict__ out) {
    __shared__ float hb[192];
    __shared__ float h1[64];
    __shared__ float h2[32];
    int g = blockIdx.x, t = threadIdx.x; // 64 threads
    for (int j = t; j < 192; j += 64) hb[j] = pooled[g * 192 + j];
    __syncthreads();
    float s = fc1b[t];
    for (int k = 0; k < 192; ++k) s += hb[k] * fc1w[k * 64 + t];
    h1[t] = fmaxf(s, 0.f);
    __syncthreads();
    if (t < 32) {
        float s2 = fc2b[t];
        for (int k = 0; k < 64; ++k) s2 += h1[k] * fc2w[k * 32 + t];
        h2[t] = fmaxf(s2, 0.f);
    }
    __syncthreads();
    if (t == 0) {
        float s3 = fc3b[0];
        for (int k = 0; k < 32; ++k) s3 += h2[k] * fc3w[k];
        out[g] = s3;
    }
}

extern "C" void kernel_launch(void* const* d_in, const int* in_sizes, int n_in,
                              void* d_out, int out_size, void* d_ws, size_t ws_size,
                              hipStream_t stream) {
    const float* x0     = (const float*)d_in[0];
    const int* ei       = (const int*)d_in[1];
    const int* batch    = (const int*)d_in[2];
    const float* W[3]   = {(const float*)d_in[3],  (const float*)d_in[11], (const float*)d_in[19]};
    const float* AS[3]  = {(const float*)d_in[4],  (const float*)d_in[12], (const float*)d_in[20]};
    const float* AD[3]  = {(const float*)d_in[5],  (const float*)d_in[13], (const float*)d_in[21]};
    const float* BI[3]  = {(const float*)d_in[6],  (const float*)d_in[14], (const float*)d_in[22]};
    const float* GA[3]  = {(const float*)d_in[7],  (const float*)d_in[15], (const float*)d_in[23]};
    const float* BE[3]  = {(const float*)d_in[8],  (const float*)d_in[16], (const float*)d_in[24]};
    const float* MU[3]  = {(const float*)d_in[9],  (const float*)d_in[17], (const float*)d_in[25]};
    const float* VA[3]  = {(const float*)d_in[10], (const float*)d_in[18], (const float*)d_in[26]};
    const float* fc1w = (const float*)d_in[27];
    const float* fc1b = (const float*)d_in[28];
    const float* fc2w = (const float*)d_in[29];
    const float* fc2b = (const float*)d_in[30];
    const float* fc3w = (const float*)d_in[31];
    const float* fc3b = (const float*)d_in[32];

    char* ws = (char*)d_ws;
    int*   rowp   = (int*)  (ws);                      // 200,004 B
    int*   cur    = (int*)  (ws + 262144);             // 200,000 B
    int*   colv   = (int*)  (ws + 524288);             // 3,400,000 B
    int*   bsum   = (int*)  (ws + 4194304);            // 1,024 B
    float* als    = (float*)(ws + 4198400);            // 800,000 B
    float* ald    = (float*)(ws + 4998400);            // 800,000 B
    float* pooled = (float*)(ws + 5798400);            // 196,608 B
    float* h_buf  = (float*)(ws + 6291456);            // 51,200,000 B
    float* x_buf  = (float*)(ws + 57491456);           // 51,200,000 B
    ushort_t* wTh = (ushort_t*)(ws + 108691456);       // 131,072 B
    ushort_t* wTl = (ushort_t*)(ws + 108822528);       // 131,072 B (end ~108.95 MB)

    const int* esrc = ei;
    const int* edst = ei + NE;
    const int NB_SCAN = (NN + 255) / 256; // 196

    // CSR build
    hipMemsetAsync(cur, 0, NN * sizeof(int), stream);
    k_deg<<<(NE + 255) / 256, 256, 0, stream>>>(edst, cur, NE);
    k_scan1<<<NB_SCAN, 256, 0, stream>>>(cur, rowp, bsum, NN);
    k_scan2<<<1, 256, 0, stream>>>(bsum, NB_SCAN);
    k_scan3<<<NB_SCAN, 256, 0, stream>>>(rowp, bsum, NN, NE + NN);
    hipMemsetAsync(cur, 0, NN * sizeof(int), stream);
    k_fill<<<(NE + NN + 255) / 256, 256, 0, stream>>>(esrc, edst, rowp, cur, colv, NE, NN);

    const int GB = (NN + 127) / 128; // 391
    int nwb = (NN + 3) / 4;

    // ---- layer 0 (K=128, HC=256, H=4)
    k_wsplit<<<(128 * 256 + 255) / 256, 256, 0, stream>>>(W[0], wTh, wTl, 128, 256);
    k_mgemm<128, 128><<<dim3(GB, 2), 256, 0, stream>>>(x0, wTh, wTl, h_buf, NN, 256);
    k_al<4><<<nwb, 256, 0, stream>>>(h_buf, AS[0], AD[0], als, ald, NN);
    k_agg<4><<<nwb, 256, 0, stream>>>(h_buf, als, ald, rowp, colv,
                                      BI[0], GA[0], BE[0], MU[0], VA[0], x_buf, NN);
    // ---- layer 1 (K=256, HC=256, H=4)
    k_wsplit<<<(256 * 256 + 255) / 256, 256, 0, stream>>>(W[1], wTh, wTl, 256, 256);
    k_mgemm<256, 128><<<dim3(GB, 2), 256, 0, stream>>>(x_buf, wTh, wTl, h_buf, NN, 256);
    k_al<4><<<nwb, 256, 0, stream>>>(h_buf, AS[1], AD[1], als, ald, NN);
    k_agg<4><<<nwb, 256, 0, stream>>>(h_buf, als, ald, rowp, colv,
                                      BI[1], GA[1], BE[1], MU[1], VA[1], x_buf, NN);
    // ---- layer 2 (K=256, HC=64, H=1)
    k_wsplit<<<(256 * 64 + 255) / 256, 256, 0, stream>>>(W[2], wTh, wTl, 256, 64);
    k_mgemm<256, 64><<<dim3(GB, 1), 256, 0, stream>>>(x_buf, wTh, wTl, h_buf, NN, 64);
    k_al<1><<<nwb, 256, 0, stream>>>(h_buf, AS[2], AD[2], als, ald, NN);
    k_agg<1><<<nwb, 256, 0, stream>>>(h_buf, als, ald, rowp, colv,
                                      BI[2], GA[2], BE[2], MU[2], VA[2], x_buf, NN);

    // readout + MLP
    k_pool<<<NGR, 64, 0, stream>>>(x_buf, batch, pooled, NN);
    k_fc<<<NGR, 64, 0, stream>>>(pooled, fc1w, fc1b, fc2w, fc2b, fc3w, fc3b,
                                 (float*)d_out);
    (void)in_sizes; (void)n_in; (void)out_size; (void)ws_size;
}